// Round 1
// 116.794 us; speedup vs baseline: 1.0039x; 1.0039x over previous
//
#include <hip/hip_runtime.h>
#include <hip/hip_bf16.h>

#define D_MODEL 1024
#define ADAPT   128
#define NUM_LIB 8
#define BATCH   1024
#define CH      32

typedef __attribute__((ext_vector_type(8))) short bf16x8;
typedef __attribute__((ext_vector_type(4))) float f32x4;

// 2x f32 -> packed bf16 (v_cvt_pk_bf16_f32 on gfx950), RNE.
__device__ __forceinline__ unsigned pk2(float a, float b) {
  __hip_bfloat162 h = __float22bfloat162_rn(make_float2(a, b));
  return *(unsigned*)&h;
}

__device__ __forceinline__ bf16x8 pk8(const float* v) {
  union { uint4 u; bf16x8 b; } o;
  o.u.x = pk2(v[0], v[1]); o.u.y = pk2(v[2], v[3]);
  o.u.z = pk2(v[4], v[5]); o.u.w = pk2(v[6], v[7]);
  return o.b;
}

// ---------------------------------------------------------------------------
// Kernel 1: partial H = X @ W1[p], bf16 MFMA, M=32, split-K x4.
// grid = (64 pairs, 2 a-halves, 4 k-quarters).
// R8 change: W1 B-fragments are loaded DIRECTLY global->VGPR (each element is
// consumed by MFMA exactly once per block, so the old LDS round-trip had
// reuse factor 1 and only cost LDS + a barrier + serialization). The 64
// independent dword loads per wave are issued BEFORE the bucket scan so the
// weight stream is in flight during bucketing; fragments persist in regs
// across the chunk loop. Lane pattern matches the MFMA B-layout exactly:
// lanes 0-15 cover 16 consecutive a at one k (64B segments), quads = 4 k's.
// NOTE (R7 post-mortem): do NOT fuse gemm1/gemm2 with a cross-block spin
// barrier — agent-scope ACQUIRE spin + threadfence cost ~125us of idle waves.
// ---------------------------------------------------------------------------
#define BK     256
#define XS_STR 264   // 256+8 shorts; /8 = 33 granules (odd) -> b128 conflict-free

__global__ __launch_bounds__(256) void gemm1_k(const float* __restrict__ x,
                                               const float* __restrict__ W1,
                                               const int* __restrict__ src,
                                               const int* __restrict__ tgt,
                                               float* __restrict__ Hp) {
  int p = blockIdx.x;
  if ((p % 9) == 0) return;            // diagonal pair: identity path
  int a0 = blockIdx.y * 64;
  int k0 = blockIdx.z * BK;            // k-quarter
  __shared__ int   nrows;
  __shared__ int   rows_l[BATCH];
  __shared__ short xs[CH * XS_STR];    // X chunk bf16 [s][kl], kl in [0,256)
  int t = threadIdx.x;
  if (t == 0) nrows = 0;
  __syncthreads();                     // nrows init (nothing in flight: cheap)
  int lane = t & 63, wvid = t >> 6, col = lane & 15, quad = lane >> 4;

  // (a) bucket loads first: oldest in vmcnt order -> near-free wait later
  int prv[4];
#pragma unroll
  for (int i = 0; i < 4; i++) {
    int s = t + 256 * i;
    prv[i] = src[s] * NUM_LIB + tgt[s];
  }
  // (b) weight B-fragments straight from global: 64 independent dword loads,
  //     ~16KB/wave in flight while the bucket scan + barrier run.
  int a = a0 + wvid * 16 + col;
  const float* wb = W1 + ((size_t)p * D_MODEL + k0 + quad * 8) * ADAPT + a;
  float wv[8][8];
#pragma unroll
  for (int kk = 0; kk < 8; kk++)
#pragma unroll
    for (int j = 0; j < 8; j++)
      wv[kk][j] = wb[(kk * 32 + j) * ADAPT];
  // (c) append rows with pair==p (consumes prv: only the 8 oldest loads)
#pragma unroll
  for (int i = 0; i < 4; i++)
    if (prv[i] == p) rows_l[atomicAdd(&nrows, 1)] = t + 256 * i;
  __syncthreads();                     // rows ready; drains weight stream too
  int n = nrows;
  if (n == 0) return;
  // (d) pack fragments in-register (VALU only, overlaps nothing to wait on)
  bf16x8 bfrag[8];
#pragma unroll
  for (int kk = 0; kk < 8; kk++) bfrag[kk] = pk8(wv[kk]);

  float* Hb = Hp + (size_t)blockIdx.z * BATCH * ADAPT;
  for (int c0 = 0; c0 < n; c0 += CH) {
    int m = min(CH, n - c0);
    {  // stage X chunk: thread (s=t&31, jg=t>>5) covers k's jg*32..+31
      int s = t & 31, jg = t >> 5;
      int row = rows_l[c0 + min(s, m - 1)];
      const float* xr = x + (size_t)row * D_MODEL + k0 + jg * 32;
      uint4* xw = (uint4*)(xs + s * XS_STR + jg * 32);
#pragma unroll
      for (int i = 0; i < 4; i++) {
        float4 v0 = *(const float4*)(xr + i * 8);
        float4 v1 = *(const float4*)(xr + i * 8 + 4);
        uint4 o;
        o.x = pk2(v0.x, v0.y); o.y = pk2(v0.z, v0.w);
        o.z = pk2(v1.x, v1.y); o.w = pk2(v1.z, v1.w);
        xw[i] = o;
      }
    }
    __syncthreads();
    f32x4 acc0 = {0.f, 0.f, 0.f, 0.f};   // rows 0-15
    f32x4 acc1 = {0.f, 0.f, 0.f, 0.f};   // rows 16-31
#pragma unroll
    for (int kk = 0; kk < 8; kk++) {
      bf16x8 af0 = *(const bf16x8*)(xs + col * XS_STR + kk * 32 + quad * 8);
      bf16x8 af1 = *(const bf16x8*)(xs + (16 + col) * XS_STR + kk * 32 + quad * 8);
      acc0 = __builtin_amdgcn_mfma_f32_16x16x32_bf16(af0, bfrag[kk], acc0, 0, 0, 0);
      acc1 = __builtin_amdgcn_mfma_f32_16x16x32_bf16(af1, bfrag[kk], acc1, 0, 0, 0);
    }
#pragma unroll
    for (int r = 0; r < 4; r++) {
      int s2 = quad * 4 + r;
      if (s2 < m)      Hb[(size_t)rows_l[c0 + s2] * ADAPT + a]      = acc0[r];
      if (s2 + 16 < m) Hb[(size_t)rows_l[c0 + s2 + 16] * ADAPT + a] = acc1[r];
    }
    if (c0 + CH < n) __syncthreads();  // protect xs before next chunk's staging
  }
}

// ---------------------------------------------------------------------------
// Kernel 2: out[rows, d0..d0+127] = relu(sum Hp + b1) @ W2[p][:, d0..] + b2
// (or copy x for diagonal pairs). grid = (64 pairs, 8 d-slices). M=32.
// R8: same direct global->reg B-fragment scheme as gemm1 (W2 LDS tile had
// reuse factor 1 too); Hp split-K reduction vectorized to float4.
// ---------------------------------------------------------------------------
#define HS_STR  136

__global__ __launch_bounds__(256) void gemm2_k(const float* __restrict__ x,
                                               const float* __restrict__ W2,
                                               const float* __restrict__ b1,
                                               const float* __restrict__ b2,
                                               const int* __restrict__ src,
                                               const int* __restrict__ tgt,
                                               const float* __restrict__ Hp,
                                               float* __restrict__ out) {
  int p = blockIdx.x;
  int d0 = blockIdx.y * 128;
  __shared__ int   nrows;
  __shared__ int   rows_l[BATCH];
  __shared__ short hs[CH * HS_STR];    // relu(sum Hp + b1) bf16 [s][k]
  int t = threadIdx.x;
  if (t == 0) nrows = 0;
  __syncthreads();
  int prv[4];
#pragma unroll
  for (int i = 0; i < 4; i++) {
    int s = t + 256 * i;
    prv[i] = src[s] * NUM_LIB + tgt[s];
  }
  if ((p % 9) == 0) {                  // identity: exact copy x -> out
#pragma unroll
    for (int i = 0; i < 4; i++)
      if (prv[i] == p) rows_l[atomicAdd(&nrows, 1)] = t + 256 * i;
    __syncthreads();
    int n = nrows;
    int j = t & 7;                     // 8 threads/row x 16 floats
    for (int c = t >> 3; c < n; c += 32) {
      size_t off = (size_t)rows_l[c] * D_MODEL + d0 + j * 16;
      float4 v0 = *(const float4*)(x + off);
      float4 v1 = *(const float4*)(x + off + 4);
      float4 v2 = *(const float4*)(x + off + 8);
      float4 v3 = *(const float4*)(x + off + 12);
      *(float4*)(out + off)      = v0;
      *(float4*)(out + off + 4)  = v1;
      *(float4*)(out + off + 8)  = v2;
      *(float4*)(out + off + 12) = v3;
    }
    return;
  }
  int lane = t & 63, wvid = t >> 6, col = lane & 15, quad = lane >> 4;
  // weight B-fragments straight from global: 64 independent dword loads.
  // b0 lane element j = W2[kk*32+quad*8+j][d0 + wvid*32 + col] (c=0),
  // b1 same with col+16 (c=1).
  const float* w2b = W2 + ((size_t)p * ADAPT + quad * 8) * D_MODEL + d0 + wvid * 32 + col;
  float wv[4][2][8];
#pragma unroll
  for (int kk = 0; kk < 4; kk++)
#pragma unroll
    for (int c = 0; c < 2; c++)
#pragma unroll
      for (int j = 0; j < 8; j++)
        wv[kk][c][j] = w2b[(size_t)(kk * 32 + j) * D_MODEL + c * 16];
#pragma unroll
  for (int i = 0; i < 4; i++)
    if (prv[i] == p) rows_l[atomicAdd(&nrows, 1)] = t + 256 * i;
  __syncthreads();                     // rows ready; drains weight stream
  int n = nrows;
  if (n == 0) return;
  bf16x8 bfragB[4][2];
#pragma unroll
  for (int kk = 0; kk < 4; kk++) {
    bfragB[kk][0] = pk8(wv[kk][0]);
    bfragB[kk][1] = pk8(wv[kk][1]);
  }
  for (int c0 = 0; c0 < n; c0 += CH) {
    int m = min(CH, n - c0);
    {  // stage H chunk: sum 4 split-K partials + bias + relu, fp32 -> bf16
      int s = t & 31, j = t >> 5;      // k-range j*16..+15
      int row = rows_l[c0 + min(s, m - 1)];
      size_t ho = (size_t)row * ADAPT + j * 16;
      const float* bb = b1 + (size_t)p * ADAPT + j * 16;
      uint4* hw = (uint4*)(hs + s * HS_STR + j * 16);
#pragma unroll
      for (int g = 0; g < 2; g++) {
        f32x4 v0 = *(const f32x4*)(bb + g * 8);
        f32x4 v1 = *(const f32x4*)(bb + g * 8 + 4);
#pragma unroll
        for (int q = 0; q < 4; q++) {
          const float* hq = Hp + (size_t)q * BATCH * ADAPT + ho + g * 8;
          v0 += *(const f32x4*)hq;
          v1 += *(const f32x4*)(hq + 4);
        }
        uint4 o;
        o.x = pk2(fmaxf(v0[0], 0.f), fmaxf(v0[1], 0.f));
        o.y = pk2(fmaxf(v0[2], 0.f), fmaxf(v0[3], 0.f));
        o.z = pk2(fmaxf(v1[0], 0.f), fmaxf(v1[1], 0.f));
        o.w = pk2(fmaxf(v1[2], 0.f), fmaxf(v1[3], 0.f));
        hw[g] = o;
      }
    }
    __syncthreads();
    f32x4 acc00 = {0.f, 0.f, 0.f, 0.f};  // rows 0-15,  d_a
    f32x4 acc01 = {0.f, 0.f, 0.f, 0.f};  // rows 0-15,  d_b
    f32x4 acc10 = {0.f, 0.f, 0.f, 0.f};  // rows 16-31, d_a
    f32x4 acc11 = {0.f, 0.f, 0.f, 0.f};  // rows 16-31, d_b
#pragma unroll
    for (int kk = 0; kk < 4; kk++) {
      bf16x8 af0 = *(const bf16x8*)(hs + col * HS_STR + kk * 32 + quad * 8);
      bf16x8 af1 = *(const bf16x8*)(hs + (16 + col) * HS_STR + kk * 32 + quad * 8);
      acc00 = __builtin_amdgcn_mfma_f32_16x16x32_bf16(af0, bfragB[kk][0], acc00, 0, 0, 0);
      acc01 = __builtin_amdgcn_mfma_f32_16x16x32_bf16(af0, bfragB[kk][1], acc01, 0, 0, 0);
      acc10 = __builtin_amdgcn_mfma_f32_16x16x32_bf16(af1, bfragB[kk][0], acc10, 0, 0, 0);
      acc11 = __builtin_amdgcn_mfma_f32_16x16x32_bf16(af1, bfragB[kk][1], acc11, 0, 0, 0);
    }
    int d_a = d0 + wvid * 32 + col;
    int d_b = d_a + 16;
    float bba = b2[(size_t)p * D_MODEL + d_a];
    float bbb = b2[(size_t)p * D_MODEL + d_b];
#pragma unroll
    for (int r = 0; r < 4; r++) {
      int s2 = quad * 4 + r;
      if (s2 < m) {
        size_t ro = (size_t)rows_l[c0 + s2] * D_MODEL;
        out[ro + d_a] = acc00[r] + bba;
        out[ro + d_b] = acc01[r] + bbb;
      }
      if (s2 + 16 < m) {
        size_t ro = (size_t)rows_l[c0 + s2 + 16] * D_MODEL;
        out[ro + d_a] = acc10[r] + bba;
        out[ro + d_b] = acc11[r] + bbb;
      }
    }
    if (c0 + CH < n) __syncthreads();  // protect hs before next chunk's staging
  }
}

// ---------------------------------------------------------------------------
extern "C" void kernel_launch(void* const* d_in, const int* in_sizes, int n_in,
                              void* d_out, int out_size, void* d_ws, size_t ws_size,
                              hipStream_t stream) {
  const float* x   = (const float*)d_in[0];
  const int*   src = (const int*)d_in[1];
  const int*   tgt = (const int*)d_in[2];
  const float* W1  = (const float*)d_in[3];
  const float* b1  = (const float*)d_in[4];
  const float* W2  = (const float*)d_in[5];
  const float* b2  = (const float*)d_in[6];
  float* out = (float*)d_out;

  // ws layout: Hp [4][1024*128] floats (split-K partials).
  float* Hp = (float*)d_ws;

  gemm1_k<<<dim3(64, 2, 4), 256, 0, stream>>>(x, W1, src, tgt, Hp);
  gemm2_k<<<dim3(64, 8), 256, 0, stream>>>(x, W2, b1, b2, src, tgt, Hp, out);
  (void)in_sizes; (void)n_in; (void)out_size; (void)ws_size;
}